// Round 1
// baseline (630.452 us; speedup 1.0000x reference)
//
#include <hip/hip_runtime.h>
#include <stdint.h>

#define NUM_CLASSES 10
#define BOX_CODE 7
#define NUM_ANCHORS 4
#define HH 500
#define WW 500
#define HW (HH * WW)                 // 250000
#define NROWS (HW * NUM_ANCHORS)     // 1,000,000
#define NBUCKET 65536
#define CAP 4096                     // candidate cap (power of 2 for bitonic)

struct Meta {
    unsigned count;   // candidate count (atomic)
    unsigned T;       // threshold bucket
};

__device__ __forceinline__ unsigned f2sort(float f) {
    unsigned b = __float_as_uint(f);
    // monotone float->uint mapping (bigger float -> bigger uint)
    return b ^ ((b & 0x80000000u) ? 0xFFFFFFFFu : 0x80000000u);
}

// Kernel 1: per-pixel max logit per anchor -> sortable keys + 16-bit histogram
__global__ void k_score_hist(const float* __restrict__ cls,
                             unsigned* __restrict__ keys,
                             unsigned* __restrict__ hist) {
    int p = blockIdx.x * blockDim.x + threadIdx.x;
    if (p >= HW) return;
    float mx0 = -INFINITY, mx1 = -INFINITY, mx2 = -INFINITY, mx3 = -INFINITY;
#pragma unroll
    for (int c = 0; c < NUM_CLASSES; ++c) {
        mx0 = fmaxf(mx0, cls[(0 * NUM_CLASSES + c) * HW + p]);
        mx1 = fmaxf(mx1, cls[(1 * NUM_CLASSES + c) * HW + p]);
        mx2 = fmaxf(mx2, cls[(2 * NUM_CLASSES + c) * HW + p]);
        mx3 = fmaxf(mx3, cls[(3 * NUM_CLASSES + c) * HW + p]);
    }
    unsigned m0 = f2sort(mx0), m1 = f2sort(mx1), m2 = f2sort(mx2), m3 = f2sort(mx3);
    uint4 v; v.x = m0; v.y = m1; v.z = m2; v.w = m3;
    *reinterpret_cast<uint4*>(&keys[(size_t)p * 4]) = v;
    atomicAdd(&hist[m0 >> 16], 1u);
    atomicAdd(&hist[m1 >> 16], 1u);
    atomicAdd(&hist[m2 >> 16], 1u);
    atomicAdd(&hist[m3 >> 16], 1u);
}

// Kernel 2: find threshold bucket T s.t. count(bucket > T) < k <= count(bucket >= T)
__global__ __launch_bounds__(1024) void k_scan(const unsigned* __restrict__ hist,
                                               Meta* __restrict__ meta, int k) {
    __shared__ unsigned arr[1024];
    const int tid = threadIdx.x;
    const int chunk = NBUCKET / 1024;       // 64
    const int base = tid * chunk;
    unsigned s = 0;
    for (int j = 0; j < chunk; ++j) s += hist[base + j];
    arr[tid] = s;
    __syncthreads();
    // inclusive suffix sum over arr (Hillis-Steele)
    for (int off = 1; off < 1024; off <<= 1) {
        unsigned v = (tid + off < 1024) ? arr[tid + off] : 0u;
        __syncthreads();
        arr[tid] += v;
        __syncthreads();
    }
    unsigned incl = arr[tid];
    unsigned excl = incl - s;
    if (excl < (unsigned)k && (unsigned)k <= incl) {
        unsigned acc = excl;
        for (int b = base + chunk - 1; b >= base; --b) {
            acc += hist[b];
            if (acc >= (unsigned)k) { meta->T = (unsigned)b; break; }
        }
    }
}

// Kernel 3: compact candidates (bucket >= T) into 64-bit ascending-sort keys
__global__ void k_compact(const unsigned* __restrict__ keys,
                          const Meta* __restrict__ meta,
                          unsigned long long* __restrict__ cand,
                          unsigned* __restrict__ count) {
    int n = blockIdx.x * blockDim.x + threadIdx.x;
    if (n >= NROWS) return;
    unsigned T = meta->T;
    unsigned m = keys[n];
    if ((m >> 16) >= T) {
        unsigned pos = atomicAdd(count, 1u);
        if (pos < CAP) {
            // ascending sort => descending score; ties => ascending index
            cand[pos] = ((unsigned long long)(m ^ 0xFFFFFFFFu) << 32) | (unsigned)n;
        }
    }
}

// Kernel 4: single-block bitonic sort of CAP keys, emit top-k row indices
__global__ __launch_bounds__(1024) void k_sort(const unsigned long long* __restrict__ cand,
                                               const Meta* __restrict__ meta,
                                               unsigned* __restrict__ topk, int k) {
    __shared__ unsigned long long key[CAP];
    const int tid = threadIdx.x;
    unsigned cnt = meta->count;
    if (cnt > CAP) cnt = CAP;
    for (int i = tid; i < CAP; i += 1024)
        key[i] = (i < (int)cnt) ? cand[i] : 0xFFFFFFFFFFFFFFFFull;
    for (unsigned size = 2; size <= CAP; size <<= 1) {
        for (unsigned stride = size >> 1; stride > 0; stride >>= 1) {
            __syncthreads();
            for (unsigned t = tid; t < CAP / 2; t += 1024) {
                unsigned lo = 2u * t - (t & (stride - 1u));
                unsigned hi = lo + stride;
                bool up = ((lo & size) == 0u);
                unsigned long long a = key[lo], b = key[hi];
                if ((a > b) == up) { key[lo] = b; key[hi] = a; }
            }
        }
    }
    __syncthreads();
    for (int j = tid; j < k; j += 1024)
        topk[j] = (unsigned)(key[j] & 0xFFFFFFFFull);
}

// Kernel 5: gather scores (sigmoid), decode boxes, dir argmax
__global__ void k_gather(const float* __restrict__ cls,
                         const float* __restrict__ bbox,
                         const float* __restrict__ dir,
                         const float* __restrict__ anchors,
                         const unsigned* __restrict__ topk,
                         float* __restrict__ out, int k) {
    int j = blockIdx.x * blockDim.x + threadIdx.x;
    if (j >= k) return;
    unsigned n = topk[j];
    unsigned p = n >> 2;
    unsigned a = n & 3u;
    // scores
#pragma unroll
    for (int c = 0; c < NUM_CLASSES; ++c) {
        float x = cls[(a * NUM_CLASSES + c) * HW + p];
        out[j * NUM_CLASSES + c] = 1.0f / (1.0f + expf(-x));
    }
    // deltas and anchors
    float d[BOX_CODE], A[BOX_CODE];
#pragma unroll
    for (int b = 0; b < BOX_CODE; ++b) {
        d[b] = bbox[(a * BOX_CODE + b) * HW + p];
        A[b] = anchors[(size_t)n * BOX_CODE + b];
    }
    // decode: anchors = (x,y,z,w,l,h,r), deltas = (xt,yt,zt,wt,lt,ht,rt)
    float za = A[2] + A[5] * 0.5f;
    float diag = sqrtf(A[4] * A[4] + A[3] * A[3]);
    float xg = d[0] * diag + A[0];
    float yg = d[1] * diag + A[1];
    float zg = d[2] * A[5] + za;
    float wg = expf(d[3]) * A[3];
    float lg = expf(d[4]) * A[4];
    float hg = expf(d[5]) * A[5];
    float rg = d[6] + A[6];
    zg = zg - hg * 0.5f;
    float* ob = out + (size_t)k * NUM_CLASSES + (size_t)j * BOX_CODE;
    ob[0] = xg; ob[1] = yg; ob[2] = zg; ob[3] = wg; ob[4] = lg; ob[5] = hg; ob[6] = rg;
    // dir argmax (tie -> 0, matching jnp.argmax first-occurrence)
    float d0 = dir[(a * 2 + 0) * HW + p];
    float d1 = dir[(a * 2 + 1) * HW + p];
    out[(size_t)k * (NUM_CLASSES + BOX_CODE) + j] = (d1 > d0) ? 1.0f : 0.0f;
}

extern "C" void kernel_launch(void* const* d_in, const int* in_sizes, int n_in,
                              void* d_out, int out_size, void* d_ws, size_t ws_size,
                              hipStream_t stream) {
    const float* cls  = (const float*)d_in[0];
    const float* bbox = (const float*)d_in[1];
    const float* dir  = (const float*)d_in[2];
    const float* anch = (const float*)d_in[3];
    float* out = (float*)d_out;
    const int k = out_size / (NUM_CLASSES + BOX_CODE + 1);   // 1000

    char* ws = (char*)d_ws;
    unsigned* keys = (unsigned*)ws;                               // 4,000,000 B
    unsigned* hist = (unsigned*)(ws + 4000000);                   // 262,144 B
    Meta* meta     = (Meta*)(ws + 4000000 + 262144);              // 8 B
    unsigned* topk = (unsigned*)(ws + 4262208);                   // 8,192 B
    unsigned long long* cand = (unsigned long long*)(ws + 4270400); // 32,768 B

    // zero histogram + meta (count, T)
    hipMemsetAsync(hist, 0, 262144 + 64, stream);

    k_score_hist<<<(HW + 255) / 256, 256, 0, stream>>>(cls, keys, hist);
    k_scan<<<1, 1024, 0, stream>>>(hist, meta, k);
    k_compact<<<(NROWS + 255) / 256, 256, 0, stream>>>(keys, meta, cand, &meta->count);
    k_sort<<<1, 1024, 0, stream>>>(cand, meta, topk, k);
    k_gather<<<(k + 255) / 256, 256, 0, stream>>>(cls, bbox, dir, anch, topk, out, k);
}

// Round 2
// 106.055 us; speedup vs baseline: 5.9446x; 5.9446x over previous
//
#include <hip/hip_runtime.h>
#include <stdint.h>

#define NUM_CLASSES 10
#define BOX_CODE 7
#define NUM_ANCHORS 4
#define HH 500
#define WW 500
#define HW (HH * WW)                 // 250000
#define NROWS (HW * NUM_ANCHORS)     // 1,000,000
#define NBUCKET 4096                 // 12-bit buckets
#define BSHIFT 20                    // key >> 20 -> bucket
#define CAP 4096                     // candidate cap (power of 2 for bitonic)

struct Meta {
    unsigned count;   // candidate count (atomic)
    unsigned T;       // threshold bucket
};

__device__ __forceinline__ unsigned f2sort(float f) {
    unsigned b = __float_as_uint(f);
    // monotone float->uint mapping (bigger float -> bigger uint)
    return b ^ ((b & 0x80000000u) ? 0xFFFFFFFFu : 0x80000000u);
}

// Kernel 1: per-pixel max logit per anchor -> sortable keys + LDS-privatized histogram
__global__ __launch_bounds__(256) void k_score_hist(const float* __restrict__ cls,
                                                    unsigned* __restrict__ keys,
                                                    unsigned* __restrict__ hist) {
    __shared__ unsigned lh[NBUCKET];
    for (int i = threadIdx.x; i < NBUCKET; i += 256) lh[i] = 0u;
    __syncthreads();

    int p = blockIdx.x * blockDim.x + threadIdx.x;
    if (p < HW) {
        float mx0 = -INFINITY, mx1 = -INFINITY, mx2 = -INFINITY, mx3 = -INFINITY;
#pragma unroll
        for (int c = 0; c < NUM_CLASSES; ++c) {
            mx0 = fmaxf(mx0, cls[(0 * NUM_CLASSES + c) * HW + p]);
            mx1 = fmaxf(mx1, cls[(1 * NUM_CLASSES + c) * HW + p]);
            mx2 = fmaxf(mx2, cls[(2 * NUM_CLASSES + c) * HW + p]);
            mx3 = fmaxf(mx3, cls[(3 * NUM_CLASSES + c) * HW + p]);
        }
        unsigned m0 = f2sort(mx0), m1 = f2sort(mx1), m2 = f2sort(mx2), m3 = f2sort(mx3);
        uint4 v; v.x = m0; v.y = m1; v.z = m2; v.w = m3;
        *reinterpret_cast<uint4*>(&keys[(size_t)p * 4]) = v;
        atomicAdd(&lh[m0 >> BSHIFT], 1u);
        atomicAdd(&lh[m1 >> BSHIFT], 1u);
        atomicAdd(&lh[m2 >> BSHIFT], 1u);
        atomicAdd(&lh[m3 >> BSHIFT], 1u);
    }
    __syncthreads();
    for (int i = threadIdx.x; i < NBUCKET; i += 256) {
        unsigned v = lh[i];
        if (v) atomicAdd(&hist[i], v);
    }
}

// Kernel 2: find threshold bucket T s.t. count(bucket > T) < k <= count(bucket >= T)
__global__ __launch_bounds__(1024) void k_scan(const unsigned* __restrict__ hist,
                                               Meta* __restrict__ meta, int k) {
    __shared__ unsigned arr[1024];
    const int tid = threadIdx.x;
    const int chunk = NBUCKET / 1024;       // 4
    const int base = tid * chunk;
    unsigned s = 0;
    for (int j = 0; j < chunk; ++j) s += hist[base + j];
    arr[tid] = s;
    __syncthreads();
    // inclusive suffix sum over arr (Hillis-Steele)
    for (int off = 1; off < 1024; off <<= 1) {
        unsigned v = (tid + off < 1024) ? arr[tid + off] : 0u;
        __syncthreads();
        arr[tid] += v;
        __syncthreads();
    }
    unsigned incl = arr[tid];
    unsigned excl = incl - s;
    if (excl < (unsigned)k && (unsigned)k <= incl) {
        unsigned acc = excl;
        for (int b = base + chunk - 1; b >= base; --b) {
            acc += hist[b];
            if (acc >= (unsigned)k) { meta->T = (unsigned)b; break; }
        }
    }
}

// Kernel 3: compact candidates (bucket >= T) into 64-bit ascending-sort keys
__global__ void k_compact(const unsigned* __restrict__ keys,
                          const Meta* __restrict__ meta,
                          unsigned long long* __restrict__ cand,
                          unsigned* __restrict__ count) {
    int n = blockIdx.x * blockDim.x + threadIdx.x;
    if (n >= NROWS) return;
    unsigned T = meta->T;
    unsigned m = keys[n];
    if ((m >> BSHIFT) >= T) {
        unsigned pos = atomicAdd(count, 1u);
        if (pos < CAP) {
            // ascending sort => descending score; ties => ascending index
            cand[pos] = ((unsigned long long)(m ^ 0xFFFFFFFFu) << 32) | (unsigned)n;
        }
    }
}

// Kernel 4: single-block bitonic sort of CAP keys, emit top-k row indices
__global__ __launch_bounds__(1024) void k_sort(const unsigned long long* __restrict__ cand,
                                               const Meta* __restrict__ meta,
                                               unsigned* __restrict__ topk, int k) {
    __shared__ unsigned long long key[CAP];
    const int tid = threadIdx.x;
    unsigned cnt = meta->count;
    if (cnt > CAP) cnt = CAP;
    for (int i = tid; i < CAP; i += 1024)
        key[i] = (i < (int)cnt) ? cand[i] : 0xFFFFFFFFFFFFFFFFull;
    for (unsigned size = 2; size <= CAP; size <<= 1) {
        for (unsigned stride = size >> 1; stride > 0; stride >>= 1) {
            __syncthreads();
            for (unsigned t = tid; t < CAP / 2; t += 1024) {
                unsigned lo = 2u * t - (t & (stride - 1u));
                unsigned hi = lo + stride;
                bool up = ((lo & size) == 0u);
                unsigned long long a = key[lo], b = key[hi];
                if ((a > b) == up) { key[lo] = b; key[hi] = a; }
            }
        }
    }
    __syncthreads();
    for (int j = tid; j < k; j += 1024)
        topk[j] = (unsigned)(key[j] & 0xFFFFFFFFull);
}

// Kernel 5: gather scores (sigmoid), decode boxes, dir argmax
__global__ void k_gather(const float* __restrict__ cls,
                         const float* __restrict__ bbox,
                         const float* __restrict__ dir,
                         const float* __restrict__ anchors,
                         const unsigned* __restrict__ topk,
                         float* __restrict__ out, int k) {
    int j = blockIdx.x * blockDim.x + threadIdx.x;
    if (j >= k) return;
    unsigned n = topk[j];
    unsigned p = n >> 2;
    unsigned a = n & 3u;
    // scores
#pragma unroll
    for (int c = 0; c < NUM_CLASSES; ++c) {
        float x = cls[(a * NUM_CLASSES + c) * HW + p];
        out[j * NUM_CLASSES + c] = 1.0f / (1.0f + expf(-x));
    }
    // deltas and anchors
    float d[BOX_CODE], A[BOX_CODE];
#pragma unroll
    for (int b = 0; b < BOX_CODE; ++b) {
        d[b] = bbox[(a * BOX_CODE + b) * HW + p];
        A[b] = anchors[(size_t)n * BOX_CODE + b];
    }
    // decode: anchors = (x,y,z,w,l,h,r), deltas = (xt,yt,zt,wt,lt,ht,rt)
    float za = A[2] + A[5] * 0.5f;
    float diag = sqrtf(A[4] * A[4] + A[3] * A[3]);
    float xg = d[0] * diag + A[0];
    float yg = d[1] * diag + A[1];
    float zg = d[2] * A[5] + za;
    float wg = expf(d[3]) * A[3];
    float lg = expf(d[4]) * A[4];
    float hg = expf(d[5]) * A[5];
    float rg = d[6] + A[6];
    zg = zg - hg * 0.5f;
    float* ob = out + (size_t)k * NUM_CLASSES + (size_t)j * BOX_CODE;
    ob[0] = xg; ob[1] = yg; ob[2] = zg; ob[3] = wg; ob[4] = lg; ob[5] = hg; ob[6] = rg;
    // dir argmax (tie -> 0, matching jnp.argmax first-occurrence)
    float d0 = dir[(a * 2 + 0) * HW + p];
    float d1 = dir[(a * 2 + 1) * HW + p];
    out[(size_t)k * (NUM_CLASSES + BOX_CODE) + j] = (d1 > d0) ? 1.0f : 0.0f;
}

extern "C" void kernel_launch(void* const* d_in, const int* in_sizes, int n_in,
                              void* d_out, int out_size, void* d_ws, size_t ws_size,
                              hipStream_t stream) {
    const float* cls  = (const float*)d_in[0];
    const float* bbox = (const float*)d_in[1];
    const float* dir  = (const float*)d_in[2];
    const float* anch = (const float*)d_in[3];
    float* out = (float*)d_out;
    const int k = out_size / (NUM_CLASSES + BOX_CODE + 1);   // 1000

    char* ws = (char*)d_ws;
    unsigned* keys = (unsigned*)ws;                               // 4,000,000 B
    unsigned* hist = (unsigned*)(ws + 4000000);                   // 16,384 B
    Meta* meta     = (Meta*)(ws + 4000000 + 16384);               // 8 B
    unsigned* topk = (unsigned*)(ws + 4016448);                   // 4,096 B
    unsigned long long* cand = (unsigned long long*)(ws + 4020544); // 32,768 B

    // zero histogram + meta (count, T)
    hipMemsetAsync(hist, 0, 16384 + 64, stream);

    k_score_hist<<<(HW + 255) / 256, 256, 0, stream>>>(cls, keys, hist);
    k_scan<<<1, 1024, 0, stream>>>(hist, meta, k);
    k_compact<<<(NROWS + 255) / 256, 256, 0, stream>>>(keys, meta, cand, &meta->count);
    k_sort<<<1, 1024, 0, stream>>>(cand, meta, topk, k);
    k_gather<<<(k + 255) / 256, 256, 0, stream>>>(cls, bbox, dir, anch, topk, out, k);
}

// Round 3
// 94.988 us; speedup vs baseline: 6.6371x; 1.1165x over previous
//
#include <hip/hip_runtime.h>
#include <stdint.h>

#define NUM_CLASSES 10
#define BOX_CODE 7
#define NUM_ANCHORS 4
#define HH 500
#define WW 500
#define HW (HH * WW)                 // 250000
#define NROWS (HW * NUM_ANCHORS)     // 1,000,000
#define NBUCKET 4096                 // 12-bit buckets
#define BSHIFT 20                    // key >> 20 -> bucket
#define CAP 4096                     // candidate cap (power of 2 for bitonic)

struct Meta {
    unsigned count;   // candidate count (atomic)
    unsigned T;       // threshold bucket
};

__device__ __forceinline__ unsigned f2sort(float f) {
    unsigned b = __float_as_uint(f);
    // monotone float->uint mapping (bigger float -> bigger uint)
    return b ^ ((b & 0x80000000u) ? 0xFFFFFFFFu : 0x80000000u);
}

// Kernel 0: zero the global histogram + meta (replaces rocclr fill, which cost 39us)
__global__ __launch_bounds__(1024) void k_zero(unsigned* __restrict__ hist,
                                               Meta* __restrict__ meta) {
    int i = threadIdx.x;
    for (int j = i; j < NBUCKET; j += 1024) hist[j] = 0u;
    if (i == 0) { meta->count = 0u; meta->T = 0u; }
}

// Kernel 1: per-pixel max logit per anchor -> sortable keys + LDS-privatized histogram.
// 4 pixels per thread, float4 channel loads, uint4 key stores.
__global__ __launch_bounds__(256) void k_score_hist(const float* __restrict__ cls,
                                                    unsigned* __restrict__ keys,
                                                    unsigned* __restrict__ hist) {
    __shared__ unsigned lh[NBUCKET];
    for (int i = threadIdx.x; i < NBUCKET; i += 256) lh[i] = 0u;
    __syncthreads();

    int t = blockIdx.x * 256 + threadIdx.x;      // 0 .. HW/4-1
    if (t < HW / 4) {
        int pix = t * 4;
        float mx[NUM_ANCHORS][4];
#pragma unroll
        for (int a = 0; a < NUM_ANCHORS; ++a)
#pragma unroll
            for (int j = 0; j < 4; ++j) mx[a][j] = -INFINITY;
#pragma unroll
        for (int a = 0; a < NUM_ANCHORS; ++a) {
#pragma unroll
            for (int c = 0; c < NUM_CLASSES; ++c) {
                float4 v = *reinterpret_cast<const float4*>(
                    &cls[(size_t)(a * NUM_CLASSES + c) * HW + pix]);
                mx[a][0] = fmaxf(mx[a][0], v.x);
                mx[a][1] = fmaxf(mx[a][1], v.y);
                mx[a][2] = fmaxf(mx[a][2], v.z);
                mx[a][3] = fmaxf(mx[a][3], v.w);
            }
        }
#pragma unroll
        for (int j = 0; j < 4; ++j) {
            unsigned m0 = f2sort(mx[0][j]);
            unsigned m1 = f2sort(mx[1][j]);
            unsigned m2 = f2sort(mx[2][j]);
            unsigned m3 = f2sort(mx[3][j]);
            uint4 kv; kv.x = m0; kv.y = m1; kv.z = m2; kv.w = m3;
            *reinterpret_cast<uint4*>(&keys[(size_t)(pix + j) * 4]) = kv;
            atomicAdd(&lh[m0 >> BSHIFT], 1u);
            atomicAdd(&lh[m1 >> BSHIFT], 1u);
            atomicAdd(&lh[m2 >> BSHIFT], 1u);
            atomicAdd(&lh[m3 >> BSHIFT], 1u);
        }
    }
    __syncthreads();
    for (int i = threadIdx.x; i < NBUCKET; i += 256) {
        unsigned v = lh[i];
        if (v) atomicAdd(&hist[i], v);
    }
}

// Kernel 2: find threshold bucket T s.t. count(bucket > T) < k <= count(bucket >= T)
__global__ __launch_bounds__(1024) void k_scan(const unsigned* __restrict__ hist,
                                               Meta* __restrict__ meta, int k) {
    __shared__ unsigned arr[1024];
    const int tid = threadIdx.x;
    const int chunk = NBUCKET / 1024;       // 4
    const int base = tid * chunk;
    unsigned s = 0;
    for (int j = 0; j < chunk; ++j) s += hist[base + j];
    arr[tid] = s;
    __syncthreads();
    // inclusive suffix sum over arr (Hillis-Steele)
    for (int off = 1; off < 1024; off <<= 1) {
        unsigned v = (tid + off < 1024) ? arr[tid + off] : 0u;
        __syncthreads();
        arr[tid] += v;
        __syncthreads();
    }
    unsigned incl = arr[tid];
    unsigned excl = incl - s;
    if (excl < (unsigned)k && (unsigned)k <= incl) {
        unsigned acc = excl;
        for (int b = base + chunk - 1; b >= base; --b) {
            acc += hist[b];
            if (acc >= (unsigned)k) { meta->T = (unsigned)b; break; }
        }
    }
}

// Kernel 3: compact candidates (bucket >= T) into 64-bit ascending-sort keys.
// uint4 loads (4 rows/thread).
__global__ void k_compact(const unsigned* __restrict__ keys,
                          const Meta* __restrict__ meta,
                          unsigned long long* __restrict__ cand,
                          unsigned* __restrict__ count) {
    int t = blockIdx.x * blockDim.x + threadIdx.x;
    if (t >= NROWS / 4) return;
    unsigned T = meta->T;
    uint4 kv = *reinterpret_cast<const uint4*>(&keys[(size_t)t * 4]);
    unsigned m[4] = {kv.x, kv.y, kv.z, kv.w};
    int n0 = t * 4;
#pragma unroll
    for (int j = 0; j < 4; ++j) {
        if ((m[j] >> BSHIFT) >= T) {
            unsigned pos = atomicAdd(count, 1u);
            if (pos < CAP) {
                // ascending sort => descending score; ties => ascending index
                cand[pos] = ((unsigned long long)(m[j] ^ 0xFFFFFFFFu) << 32)
                            | (unsigned)(n0 + j);
            }
        }
    }
}

// Kernel 4: single-block bitonic sort over next-pow2(count) keys, emit top-k indices
__global__ __launch_bounds__(1024) void k_sort(const unsigned long long* __restrict__ cand,
                                               const Meta* __restrict__ meta,
                                               unsigned* __restrict__ topk, int k) {
    __shared__ unsigned long long key[CAP];
    const int tid = threadIdx.x;
    unsigned cnt = meta->count;
    if (cnt > CAP) cnt = CAP;
    unsigned n2 = 1024;                      // >= k
    while (n2 < cnt) n2 <<= 1;               // next pow2 >= cnt (<= CAP)
    for (unsigned i = tid; i < n2; i += 1024)
        key[i] = (i < cnt) ? cand[i] : 0xFFFFFFFFFFFFFFFFull;
    for (unsigned size = 2; size <= n2; size <<= 1) {
        for (unsigned stride = size >> 1; stride > 0; stride >>= 1) {
            __syncthreads();
            for (unsigned t = tid; t < n2 / 2; t += 1024) {
                unsigned lo = 2u * t - (t & (stride - 1u));
                unsigned hi = lo + stride;
                bool up = ((lo & size) == 0u);
                unsigned long long a = key[lo], b = key[hi];
                if ((a > b) == up) { key[lo] = b; key[hi] = a; }
            }
        }
    }
    __syncthreads();
    for (int j = tid; j < k; j += 1024)
        topk[j] = (unsigned)(key[j] & 0xFFFFFFFFull);
}

// Kernel 5: gather scores (sigmoid), decode boxes, dir argmax
__global__ void k_gather(const float* __restrict__ cls,
                         const float* __restrict__ bbox,
                         const float* __restrict__ dir,
                         const float* __restrict__ anchors,
                         const unsigned* __restrict__ topk,
                         float* __restrict__ out, int k) {
    int j = blockIdx.x * blockDim.x + threadIdx.x;
    if (j >= k) return;
    unsigned n = topk[j];
    unsigned p = n >> 2;
    unsigned a = n & 3u;
    // scores
#pragma unroll
    for (int c = 0; c < NUM_CLASSES; ++c) {
        float x = cls[(a * NUM_CLASSES + c) * HW + p];
        out[j * NUM_CLASSES + c] = 1.0f / (1.0f + expf(-x));
    }
    // deltas and anchors
    float d[BOX_CODE], A[BOX_CODE];
#pragma unroll
    for (int b = 0; b < BOX_CODE; ++b) {
        d[b] = bbox[(a * BOX_CODE + b) * HW + p];
        A[b] = anchors[(size_t)n * BOX_CODE + b];
    }
    // decode: anchors = (x,y,z,w,l,h,r), deltas = (xt,yt,zt,wt,lt,ht,rt)
    float za = A[2] + A[5] * 0.5f;
    float diag = sqrtf(A[4] * A[4] + A[3] * A[3]);
    float xg = d[0] * diag + A[0];
    float yg = d[1] * diag + A[1];
    float zg = d[2] * A[5] + za;
    float wg = expf(d[3]) * A[3];
    float lg = expf(d[4]) * A[4];
    float hg = expf(d[5]) * A[5];
    float rg = d[6] + A[6];
    zg = zg - hg * 0.5f;
    float* ob = out + (size_t)k * NUM_CLASSES + (size_t)j * BOX_CODE;
    ob[0] = xg; ob[1] = yg; ob[2] = zg; ob[3] = wg; ob[4] = lg; ob[5] = hg; ob[6] = rg;
    // dir argmax (tie -> 0, matching jnp.argmax first-occurrence)
    float d0 = dir[(a * 2 + 0) * HW + p];
    float d1 = dir[(a * 2 + 1) * HW + p];
    out[(size_t)k * (NUM_CLASSES + BOX_CODE) + j] = (d1 > d0) ? 1.0f : 0.0f;
}

extern "C" void kernel_launch(void* const* d_in, const int* in_sizes, int n_in,
                              void* d_out, int out_size, void* d_ws, size_t ws_size,
                              hipStream_t stream) {
    const float* cls  = (const float*)d_in[0];
    const float* bbox = (const float*)d_in[1];
    const float* dir  = (const float*)d_in[2];
    const float* anch = (const float*)d_in[3];
    float* out = (float*)d_out;
    const int k = out_size / (NUM_CLASSES + BOX_CODE + 1);   // 1000

    char* ws = (char*)d_ws;
    unsigned* keys = (unsigned*)ws;                               // 4,000,000 B
    unsigned* hist = (unsigned*)(ws + 4000000);                   // 16,384 B
    Meta* meta     = (Meta*)(ws + 4000000 + 16384);               // 8 B
    unsigned* topk = (unsigned*)(ws + 4016448);                   // 4,096 B
    unsigned long long* cand = (unsigned long long*)(ws + 4020544); // 32,768 B

    k_zero<<<1, 1024, 0, stream>>>(hist, meta);
    k_score_hist<<<(HW / 4 + 255) / 256, 256, 0, stream>>>(cls, keys, hist);
    k_scan<<<1, 1024, 0, stream>>>(hist, meta, k);
    k_compact<<<(NROWS / 4 + 255) / 256, 256, 0, stream>>>(keys, meta, cand, &meta->count);
    k_sort<<<1, 1024, 0, stream>>>(cand, meta, topk, k);
    k_gather<<<(k + 255) / 256, 256, 0, stream>>>(cls, bbox, dir, anch, topk, out, k);
}